// Round 1
// baseline (16557.124 us; speedup 1.0000x reference)
//
#include <hip/hip_runtime.h>

#define BB 32
#define TT 2048
#define DD 256
#define HH 512

__device__ __forceinline__ float tanh_f(float x) {
    // tanh(x) = 1 - 2/(e^{2x}+1); handles +-inf saturation correctly
    float e = __expf(2.f * x);
    return 1.f - 2.f / (e + 1.f);
}

// ---------------------------------------------------------------------------
// Kernel A: xw[t][b][n] = bh[n] + sum_d X[b][t][d] * Wxh[d][n]
// Written IN PLACE into the d_out Y region (same [T][B][H] layout); the scan
// kernel reads xw[t,b,n] and overwrites it with Y[t,b,n].
// M = B*T (row r = b*T + t), N = H, K = D. 64x64 tile, 256 threads, K-step 16.
// ---------------------------------------------------------------------------
__global__ __launch_bounds__(256) void xw_gemm(const float* __restrict__ X,
                                               const float* __restrict__ Wxh,
                                               const float* __restrict__ bh,
                                               float* __restrict__ out) {
    __shared__ float As[16][68];  // [k][m], padded
    __shared__ float Bs[16][68];  // [k][n], padded
    const int tid = threadIdx.x;
    const int r0 = blockIdx.x * 64;
    const int n0 = blockIdx.y * 64;
    const int ty = tid >> 4, tx = tid & 15;

    float acc[4][4];
#pragma unroll
    for (int i = 0; i < 4; i++)
#pragma unroll
        for (int j = 0; j < 4; j++) acc[i][j] = 0.f;

    const int arow = tid >> 2;         // 0..63
    const int akq  = (tid & 3) * 4;    // 0,4,8,12
    const int brow = tid >> 4;         // 0..15
    const int bq   = (tid & 15) * 4;   // 0..60

    for (int k0 = 0; k0 < DD; k0 += 16) {
        float4 a4 = *reinterpret_cast<const float4*>(
            &X[(size_t)(r0 + arow) * DD + k0 + akq]);
        As[akq + 0][arow] = a4.x;
        As[akq + 1][arow] = a4.y;
        As[akq + 2][arow] = a4.z;
        As[akq + 3][arow] = a4.w;
        float4 b4 = *reinterpret_cast<const float4*>(
            &Wxh[(size_t)(k0 + brow) * HH + n0 + bq]);
        *reinterpret_cast<float4*>(&Bs[brow][bq]) = b4;
        __syncthreads();
#pragma unroll
        for (int kk = 0; kk < 16; kk++) {
            float a0 = As[kk][ty * 4 + 0];
            float a1 = As[kk][ty * 4 + 1];
            float a2 = As[kk][ty * 4 + 2];
            float a3 = As[kk][ty * 4 + 3];
            float4 bv = *reinterpret_cast<const float4*>(&Bs[kk][tx * 4]);
            acc[0][0] += a0 * bv.x; acc[0][1] += a0 * bv.y; acc[0][2] += a0 * bv.z; acc[0][3] += a0 * bv.w;
            acc[1][0] += a1 * bv.x; acc[1][1] += a1 * bv.y; acc[1][2] += a1 * bv.z; acc[1][3] += a1 * bv.w;
            acc[2][0] += a2 * bv.x; acc[2][1] += a2 * bv.y; acc[2][2] += a2 * bv.z; acc[2][3] += a2 * bv.w;
            acc[3][0] += a3 * bv.x; acc[3][1] += a3 * bv.y; acc[3][2] += a3 * bv.z; acc[3][3] += a3 * bv.w;
        }
        __syncthreads();
    }
    float4 bias = *reinterpret_cast<const float4*>(&bh[n0 + tx * 4]);
#pragma unroll
    for (int i = 0; i < 4; i++) {
        int r = r0 + ty * 4 + i;
        int b = r >> 11;          // r / T
        int t = r & (TT - 1);     // r % T
        float4 o;
        o.x = acc[i][0] + bias.x;
        o.y = acc[i][1] + bias.y;
        o.z = acc[i][2] + bias.z;
        o.w = acc[i][3] + bias.w;
        *reinterpret_cast<float4*>(
            &out[((size_t)t * BB + b) * HH + n0 + tx * 4]) = o;
    }
}

// ---------------------------------------------------------------------------
// Kernel B: the sequential scan. One workgroup per batch element (32 WGs).
// 1024 threads: thread owns 4 consecutive outputs (nb..nb+3) over a 64-wide
// k-chunk (kq). Whh streamed from L2 each step (1 MB/step/WG). h kept in LDS.
// Reads xw in place from the Y buffer, overwrites with h.
// ---------------------------------------------------------------------------
__global__ __launch_bounds__(1024) void scan_kernel(const float* __restrict__ Whh,
                                                    float* __restrict__ Y) {
    __shared__ float hl[HH];
    __shared__ float part[8][HH];
    const int tid = threadIdx.x;
    const int b = blockIdx.x;
    if (tid < HH) hl[tid] = 0.f;
    __syncthreads();

    const int nb = (tid & 127) * 4;  // 4 consecutive output columns
    const int kq = tid >> 7;         // 0..7 k-chunk
    const int k0 = kq * 64;

    for (int t = 0; t < TT; t++) {
        float4 acc = make_float4(0.f, 0.f, 0.f, 0.f);
#pragma unroll 4
        for (int k = k0; k < k0 + 64; k += 4) {
            float4 h4 = *reinterpret_cast<const float4*>(&hl[k]);
            float4 w0 = *reinterpret_cast<const float4*>(&Whh[(size_t)(k + 0) * HH + nb]);
            float4 w1 = *reinterpret_cast<const float4*>(&Whh[(size_t)(k + 1) * HH + nb]);
            float4 w2 = *reinterpret_cast<const float4*>(&Whh[(size_t)(k + 2) * HH + nb]);
            float4 w3 = *reinterpret_cast<const float4*>(&Whh[(size_t)(k + 3) * HH + nb]);
            acc.x += h4.x * w0.x + h4.y * w1.x + h4.z * w2.x + h4.w * w3.x;
            acc.y += h4.x * w0.y + h4.y * w1.y + h4.z * w2.y + h4.w * w3.y;
            acc.z += h4.x * w0.z + h4.y * w1.z + h4.z * w2.z + h4.w * w3.z;
            acc.w += h4.x * w0.w + h4.y * w1.w + h4.z * w2.w + h4.w * w3.w;
        }
        *reinterpret_cast<float4*>(&part[kq][nb]) = acc;
        __syncthreads();
        if (tid < HH) {
            const int n = tid;
            float s = part[0][n] + part[1][n] + part[2][n] + part[3][n] +
                      part[4][n] + part[5][n] + part[6][n] + part[7][n];
            size_t idx = ((size_t)t * BB + b) * HH + n;
            s += Y[idx];          // xw (+bh), precomputed in place
            float hn = tanh_f(s);
            hl[n] = hn;           // safe: all k-loop reads of hl happened before barrier
            Y[idx] = hn;
        }
        __syncthreads();
    }
}

// ---------------------------------------------------------------------------
// Kernel C: attention, one WG per batch. Uses the identity
//   scores[b,t] = Y[t,b,:] . v[b],  v[b] = KW @ (QW^T Y[T-1,b])
// so K = Y@KW is never materialized. Then softmax over t, then context.
// ---------------------------------------------------------------------------
__global__ __launch_bounds__(512) void attn_kernel(const float* __restrict__ QW,
                                                   const float* __restrict__ KW,
                                                   const float* __restrict__ Y,
                                                   float* __restrict__ c) {
    __shared__ float yl[HH];
    __shared__ float q0[DD];
    __shared__ float vv[HH];
    __shared__ float sc[TT];
    __shared__ float red[16];
    const int tid = threadIdx.x;
    const int b = blockIdx.x;
    const int w = tid >> 6;  // wave 0..7
    const int l = tid & 63;  // lane

    // phase 0: last hidden state
    if (tid < HH) yl[tid] = Y[((size_t)(TT - 1) * BB + b) * HH + tid];
    __syncthreads();

    // phase 1: Q0[d] = sum_h yl[h] * QW[h][d]
    if (tid < DD) {
        float s = 0.f;
#pragma unroll 8
        for (int h = 0; h < HH; h++) s += yl[h] * QW[(size_t)h * DD + tid];
        q0[tid] = s;
    }
    __syncthreads();

    // phase 2: v[n] = sum_d KW[n][d] * q0[d]
    {
        float s = 0.f;
        const int n = tid;
#pragma unroll 4
        for (int d = 0; d < DD; d += 4) {
            float4 kw = *reinterpret_cast<const float4*>(&KW[(size_t)n * DD + d]);
            float4 q4 = *reinterpret_cast<const float4*>(&q0[d]);
            s += kw.x * q4.x + kw.y * q4.y + kw.z * q4.z + kw.w * q4.w;
        }
        vv[n] = s;
    }
    __syncthreads();

    // phase 3: scores[t] = tanh(Y[t,b,:] . v), one t per wave per iteration
    for (int i = 0; i < TT / 8; i++) {
        int t = i * 8 + w;
        const float* yr = &Y[((size_t)t * BB + b) * HH + l * 8];
        float4 y0 = *reinterpret_cast<const float4*>(yr);
        float4 y1 = *reinterpret_cast<const float4*>(yr + 4);
        float4 v0 = *reinterpret_cast<const float4*>(&vv[l * 8]);
        float4 v1 = *reinterpret_cast<const float4*>(&vv[l * 8 + 4]);
        float s = y0.x * v0.x + y0.y * v0.y + y0.z * v0.z + y0.w * v0.w +
                  y1.x * v1.x + y1.y * v1.y + y1.z * v1.z + y1.w * v1.w;
#pragma unroll
        for (int off = 32; off > 0; off >>= 1) s += __shfl_xor(s, off);
        if (l == 0) sc[t] = tanh_f(s);
    }
    __syncthreads();

    // phase 4: softmax over sc[0..TT)
    float m = -1e30f;
    for (int i = tid; i < TT; i += 512) m = fmaxf(m, sc[i]);
#pragma unroll
    for (int off = 32; off > 0; off >>= 1) m = fmaxf(m, __shfl_xor(m, off));
    if (l == 0) red[w] = m;
    __syncthreads();
    float gm = red[0];
#pragma unroll
    for (int i = 1; i < 8; i++) gm = fmaxf(gm, red[i]);

    float ls = 0.f;
    for (int i = tid; i < TT; i += 512) {
        float e = __expf(sc[i] - gm);
        sc[i] = e;
        ls += e;
    }
#pragma unroll
    for (int off = 32; off > 0; off >>= 1) ls += __shfl_xor(ls, off);
    __syncthreads();          // gm reads done before red reuse
    if (l == 0) red[8 + w] = ls;
    __syncthreads();
    float tot = 0.f;
#pragma unroll
    for (int i = 0; i < 8; i++) tot += red[8 + i];
    float inv = 1.f / tot;
    for (int i = tid; i < TT; i += 512) sc[i] *= inv;
    __syncthreads();

    // phase 5: context c[b,n] = sum_t A[t] * Y[t,b,n]
    {
        const int n = tid;
        float acc = 0.f;
        for (int t = 0; t < TT; t += 4) {
            float4 a4 = *reinterpret_cast<const float4*>(&sc[t]);
            acc += a4.x * Y[((size_t)(t + 0) * BB + b) * HH + n];
            acc += a4.y * Y[((size_t)(t + 1) * BB + b) * HH + n];
            acc += a4.z * Y[((size_t)(t + 2) * BB + b) * HH + n];
            acc += a4.w * Y[((size_t)(t + 3) * BB + b) * HH + n];
        }
        c[(size_t)b * HH + n] = acc;
    }
}

// ---------------------------------------------------------------------------
extern "C" void kernel_launch(void* const* d_in, const int* in_sizes, int n_in,
                              void* d_out, int out_size, void* d_ws, size_t ws_size,
                              hipStream_t stream) {
    const float* X   = (const float*)d_in[0];
    const float* Wxh = (const float*)d_in[1];
    const float* Whh = (const float*)d_in[2];
    const float* bh  = (const float*)d_in[3];
    const float* QW  = (const float*)d_in[4];
    const float* KW  = (const float*)d_in[5];
    float* out  = (float*)d_out;
    float* Ybuf = out;                              // [T][B][H]
    float* cbuf = out + (size_t)TT * BB * HH;       // [B][H]

    dim3 ga(BB * TT / 64, HH / 64);
    xw_gemm<<<ga, 256, 0, stream>>>(X, Wxh, bh, Ybuf);
    scan_kernel<<<BB, 1024, 0, stream>>>(Whh, Ybuf);
    attn_kernel<<<BB, 512, 0, stream>>>(QW, KW, Ybuf, cbuf);
}

// Round 2
// 11039.604 us; speedup vs baseline: 1.4998x; 1.4998x over previous
//
#include <hip/hip_runtime.h>

#define BB 32
#define TT 2048
#define DD 256
#define HH 512
#define NSL 8     // column slices per batch
#define SLW 64    // slice width (columns per WG)
#define KPT 64    // k-range per thread (512 threads: 8 waves x 64 lanes)

__device__ __forceinline__ float tanh_f(float x) {
    float e = __expf(2.f * x);
    return 1.f - 2.f / (e + 1.f);
}

// ---------------------------------------------------------------------------
// zero the sync counters in d_ws (d_ws is poisoned 0xAA before every launch)
// ---------------------------------------------------------------------------
__global__ void zero_flags(unsigned int* f) { f[threadIdx.x] = 0u; }

// ---------------------------------------------------------------------------
// Kernel A: xw[t][b][n] = bh[n] + sum_d X[b][t][d] * Wxh[d][n]
// Written IN PLACE into the d_out Y region (same [T][B][H] layout).
// ---------------------------------------------------------------------------
__global__ __launch_bounds__(256) void xw_gemm(const float* __restrict__ X,
                                               const float* __restrict__ Wxh,
                                               const float* __restrict__ bh,
                                               float* __restrict__ out) {
    __shared__ float As[16][68];
    __shared__ float Bs[16][68];
    const int tid = threadIdx.x;
    const int r0 = blockIdx.x * 64;
    const int n0 = blockIdx.y * 64;
    const int ty = tid >> 4, tx = tid & 15;

    float acc[4][4];
#pragma unroll
    for (int i = 0; i < 4; i++)
#pragma unroll
        for (int j = 0; j < 4; j++) acc[i][j] = 0.f;

    const int arow = tid >> 2;
    const int akq  = (tid & 3) * 4;
    const int brow = tid >> 4;
    const int bq   = (tid & 15) * 4;

    for (int k0 = 0; k0 < DD; k0 += 16) {
        float4 a4 = *reinterpret_cast<const float4*>(
            &X[(size_t)(r0 + arow) * DD + k0 + akq]);
        As[akq + 0][arow] = a4.x;
        As[akq + 1][arow] = a4.y;
        As[akq + 2][arow] = a4.z;
        As[akq + 3][arow] = a4.w;
        float4 b4 = *reinterpret_cast<const float4*>(
            &Wxh[(size_t)(k0 + brow) * HH + n0 + bq]);
        *reinterpret_cast<float4*>(&Bs[brow][bq]) = b4;
        __syncthreads();
#pragma unroll
        for (int kk = 0; kk < 16; kk++) {
            float a0 = As[kk][ty * 4 + 0];
            float a1 = As[kk][ty * 4 + 1];
            float a2 = As[kk][ty * 4 + 2];
            float a3 = As[kk][ty * 4 + 3];
            float4 bv = *reinterpret_cast<const float4*>(&Bs[kk][tx * 4]);
            acc[0][0] += a0 * bv.x; acc[0][1] += a0 * bv.y; acc[0][2] += a0 * bv.z; acc[0][3] += a0 * bv.w;
            acc[1][0] += a1 * bv.x; acc[1][1] += a1 * bv.y; acc[1][2] += a1 * bv.z; acc[1][3] += a1 * bv.w;
            acc[2][0] += a2 * bv.x; acc[2][1] += a2 * bv.y; acc[2][2] += a2 * bv.z; acc[2][3] += a2 * bv.w;
            acc[3][0] += a3 * bv.x; acc[3][1] += a3 * bv.y; acc[3][2] += a3 * bv.z; acc[3][3] += a3 * bv.w;
        }
        __syncthreads();
    }
    float4 bias = *reinterpret_cast<const float4*>(&bh[n0 + tx * 4]);
#pragma unroll
    for (int i = 0; i < 4; i++) {
        int r = r0 + ty * 4 + i;
        int b = r >> 11;
        int t = r & (TT - 1);
        float4 o;
        o.x = acc[i][0] + bias.x;
        o.y = acc[i][1] + bias.y;
        o.z = acc[i][2] + bias.z;
        o.w = acc[i][3] + bias.w;
        *reinterpret_cast<float4*>(
            &out[((size_t)t * BB + b) * HH + n0 + tx * 4]) = o;
    }
}

// ---------------------------------------------------------------------------
// Kernel B: distributed scan. 256 WGs = 32 batches x 8 column slices,
// one WG per CU. Whh slice [512][64] lives in REGISTERS (64/thread).
// Per step: slice matvec -> tanh -> write slice into Y (Y doubles as the
// h-exchange buffer) -> monotonic counter sync (agent scope) -> reload h.
// blockIdx = s*32+b so a batch's 8 peers share an XCD (bid%8 == b%8).
// ---------------------------------------------------------------------------
__global__ __launch_bounds__(512) void scan_kernel(const float* __restrict__ Whh,
                                                   float* __restrict__ Y,
                                                   unsigned int* __restrict__ cnt) {
    __shared__ float h_lds[HH];
    __shared__ float part[NSL][SLW];
    const int tid = threadIdx.x;
    const int bid = blockIdx.x;
    const int s = bid >> 5;       // slice 0..7
    const int b = bid & 31;       // batch 0..31
    const int n0 = s * SLW;
    const int n  = tid & 63;      // column within slice
    const int kq = tid >> 6;      // 0..7
    const int k0 = kq * KPT;

    // one-time: load Whh slice into registers, w[j] = Whh[k0+j][n0+n]
    float w[KPT];
#pragma unroll
    for (int j = 0; j < KPT; j++)
        w[j] = Whh[(size_t)(k0 + j) * HH + n0 + n];

    h_lds[tid] = 0.f;   // tid covers 0..511 == HH
    __syncthreads();

    unsigned int* flag = &cnt[b * 16];   // 64B-padded counters

    // xw for t=0 (in place in Y)
    float xw_cur = 0.f;
    if (tid < SLW) xw_cur = Y[(size_t)b * HH + n0 + n];

    for (int t = 0; t < TT; t++) {
        // slice matvec: part over k-chunks
        float a0 = 0.f, a1 = 0.f, a2 = 0.f, a3 = 0.f;
#pragma unroll
        for (int j = 0; j < KPT; j += 4) {
            float4 h4 = *reinterpret_cast<const float4*>(&h_lds[k0 + j]);
            a0 += h4.x * w[j + 0];
            a1 += h4.y * w[j + 1];
            a2 += h4.z * w[j + 2];
            a3 += h4.w * w[j + 3];
        }
        part[kq][n] = (a0 + a1) + (a2 + a3);
        __syncthreads();

        if (tid < SLW) {
            float ssum = part[0][n] + part[1][n] + part[2][n] + part[3][n] +
                         part[4][n] + part[5][n] + part[6][n] + part[7][n] +
                         xw_cur;
            float hn = tanh_f(ssum);
            Y[((size_t)t * BB + b) * HH + n0 + n] = hn;
        }
        // __syncthreads drains all waves' stores (vmcnt) before the flag
        __syncthreads();

        if (tid == 0)
            __hip_atomic_fetch_add(flag, 1u, __ATOMIC_RELEASE,
                                   __HIP_MEMORY_SCOPE_AGENT);

        if (t + 1 < TT) {
            // prefetch next xw while waiting (xw is constant data; safe)
            if (tid < SLW)
                xw_cur = Y[((size_t)(t + 1) * BB + b) * HH + n0 + n];
            if (tid == 0) {
                const unsigned int target = (unsigned)(NSL * (t + 1));
                while (__hip_atomic_load(flag, __ATOMIC_ACQUIRE,
                                         __HIP_MEMORY_SCOPE_AGENT) < target)
                    __builtin_amdgcn_s_sleep(2);
            }
            __syncthreads();
            // reload full h_t from Y[t][b][:]
            h_lds[tid] = Y[((size_t)t * BB + b) * HH + tid];
            __syncthreads();
        }
    }
}

// ---------------------------------------------------------------------------
// Kernel C: attention, one WG per batch.
//   scores[b,t] = tanh(Y[t,b,:] . v[b]),  v[b] = KW @ (QW^T Y[T-1,b])
// ---------------------------------------------------------------------------
__global__ __launch_bounds__(512) void attn_kernel(const float* __restrict__ QW,
                                                   const float* __restrict__ KW,
                                                   const float* __restrict__ Y,
                                                   float* __restrict__ c) {
    __shared__ float yl[HH];
    __shared__ float q0[DD];
    __shared__ float vv[HH];
    __shared__ float sc[TT];
    __shared__ float red[16];
    const int tid = threadIdx.x;
    const int b = blockIdx.x;
    const int w = tid >> 6;
    const int l = tid & 63;

    if (tid < HH) yl[tid] = Y[((size_t)(TT - 1) * BB + b) * HH + tid];
    __syncthreads();

    if (tid < DD) {
        float s = 0.f;
#pragma unroll 8
        for (int h = 0; h < HH; h++) s += yl[h] * QW[(size_t)h * DD + tid];
        q0[tid] = s;
    }
    __syncthreads();

    {
        float s = 0.f;
        const int n = tid;
#pragma unroll 4
        for (int d = 0; d < DD; d += 4) {
            float4 kw = *reinterpret_cast<const float4*>(&KW[(size_t)n * DD + d]);
            float4 q4 = *reinterpret_cast<const float4*>(&q0[d]);
            s += kw.x * q4.x + kw.y * q4.y + kw.z * q4.z + kw.w * q4.w;
        }
        vv[n] = s;
    }
    __syncthreads();

    for (int i = 0; i < TT / 8; i++) {
        int t = i * 8 + w;
        const float* yr = &Y[((size_t)t * BB + b) * HH + l * 8];
        float4 y0 = *reinterpret_cast<const float4*>(yr);
        float4 y1 = *reinterpret_cast<const float4*>(yr + 4);
        float4 v0 = *reinterpret_cast<const float4*>(&vv[l * 8]);
        float4 v1 = *reinterpret_cast<const float4*>(&vv[l * 8 + 4]);
        float s = y0.x * v0.x + y0.y * v0.y + y0.z * v0.z + y0.w * v0.w +
                  y1.x * v1.x + y1.y * v1.y + y1.z * v1.z + y1.w * v1.w;
#pragma unroll
        for (int off = 32; off > 0; off >>= 1) s += __shfl_xor(s, off);
        if (l == 0) sc[t] = tanh_f(s);
    }
    __syncthreads();

    float m = -1e30f;
    for (int i = tid; i < TT; i += 512) m = fmaxf(m, sc[i]);
#pragma unroll
    for (int off = 32; off > 0; off >>= 1) m = fmaxf(m, __shfl_xor(m, off));
    if (l == 0) red[w] = m;
    __syncthreads();
    float gm = red[0];
#pragma unroll
    for (int i = 1; i < 8; i++) gm = fmaxf(gm, red[i]);

    float ls = 0.f;
    for (int i = tid; i < TT; i += 512) {
        float e = __expf(sc[i] - gm);
        sc[i] = e;
        ls += e;
    }
#pragma unroll
    for (int off = 32; off > 0; off >>= 1) ls += __shfl_xor(ls, off);
    __syncthreads();
    if (l == 0) red[8 + w] = ls;
    __syncthreads();
    float tot = 0.f;
#pragma unroll
    for (int i = 0; i < 8; i++) tot += red[8 + i];
    float inv = 1.f / tot;
    for (int i = tid; i < TT; i += 512) sc[i] *= inv;
    __syncthreads();

    {
        const int n = tid;
        float acc = 0.f;
        for (int t = 0; t < TT; t += 4) {
            float4 a4 = *reinterpret_cast<const float4*>(&sc[t]);
            acc += a4.x * Y[((size_t)(t + 0) * BB + b) * HH + n];
            acc += a4.y * Y[((size_t)(t + 1) * BB + b) * HH + n];
            acc += a4.z * Y[((size_t)(t + 2) * BB + b) * HH + n];
            acc += a4.w * Y[((size_t)(t + 3) * BB + b) * HH + n];
        }
        c[(size_t)b * HH + n] = acc;
    }
}

// ---------------------------------------------------------------------------
extern "C" void kernel_launch(void* const* d_in, const int* in_sizes, int n_in,
                              void* d_out, int out_size, void* d_ws, size_t ws_size,
                              hipStream_t stream) {
    const float* X   = (const float*)d_in[0];
    const float* Wxh = (const float*)d_in[1];
    const float* Whh = (const float*)d_in[2];
    const float* bh  = (const float*)d_in[3];
    const float* QW  = (const float*)d_in[4];
    const float* KW  = (const float*)d_in[5];
    float* out  = (float*)d_out;
    float* Ybuf = out;                              // [T][B][H]
    float* cbuf = out + (size_t)TT * BB * HH;       // [B][H]
    unsigned int* flags = (unsigned int*)d_ws;      // 32 x 16 uints (64B pad)

    zero_flags<<<1, 512, 0, stream>>>(flags);
    dim3 ga(BB * TT / 64, HH / 64);
    xw_gemm<<<ga, 256, 0, stream>>>(X, Wxh, bh, Ybuf);
    scan_kernel<<<BB * NSL, 512, 0, stream>>>(Whh, Ybuf, flags);
    attn_kernel<<<BB, 512, 0, stream>>>(QW, KW, Ybuf, cbuf);
}

// Round 3
// 3361.629 us; speedup vs baseline: 4.9253x; 3.2840x over previous
//
#include <hip/hip_runtime.h>

#define BB 32
#define TT 2048
#define DD 256
#define HH 512
#define NSL 8     // column slices per batch
#define SLW 64    // slice width (columns per WG)
#define KPT 64    // k-range per thread (512 threads: 8 waves x 64 lanes)

__device__ __forceinline__ float tanh_f(float x) {
    float e = __expf(2.f * x);
    return 1.f - 2.f / (e + 1.f);
}

// ---------------------------------------------------------------------------
// Kernel A: xw[t][b][n] = bh[n] + sum_d X[b][t][d] * Wxh[d][n]
// Written IN PLACE into the d_out Y region (same [T][B][H] layout).
// ---------------------------------------------------------------------------
__global__ __launch_bounds__(256) void xw_gemm(const float* __restrict__ X,
                                               const float* __restrict__ Wxh,
                                               const float* __restrict__ bh,
                                               float* __restrict__ out) {
    __shared__ float As[16][68];
    __shared__ float Bs[16][68];
    const int tid = threadIdx.x;
    const int r0 = blockIdx.x * 64;
    const int n0 = blockIdx.y * 64;
    const int ty = tid >> 4, tx = tid & 15;

    float acc[4][4];
#pragma unroll
    for (int i = 0; i < 4; i++)
#pragma unroll
        for (int j = 0; j < 4; j++) acc[i][j] = 0.f;

    const int arow = tid >> 2;
    const int akq  = (tid & 3) * 4;
    const int brow = tid >> 4;
    const int bq   = (tid & 15) * 4;

    for (int k0 = 0; k0 < DD; k0 += 16) {
        float4 a4 = *reinterpret_cast<const float4*>(
            &X[(size_t)(r0 + arow) * DD + k0 + akq]);
        As[akq + 0][arow] = a4.x;
        As[akq + 1][arow] = a4.y;
        As[akq + 2][arow] = a4.z;
        As[akq + 3][arow] = a4.w;
        float4 b4 = *reinterpret_cast<const float4*>(
            &Wxh[(size_t)(k0 + brow) * HH + n0 + bq]);
        *reinterpret_cast<float4*>(&Bs[brow][bq]) = b4;
        __syncthreads();
#pragma unroll
        for (int kk = 0; kk < 16; kk++) {
            float a0 = As[kk][ty * 4 + 0];
            float a1 = As[kk][ty * 4 + 1];
            float a2 = As[kk][ty * 4 + 2];
            float a3 = As[kk][ty * 4 + 3];
            float4 bv = *reinterpret_cast<const float4*>(&Bs[kk][tx * 4]);
            acc[0][0] += a0 * bv.x; acc[0][1] += a0 * bv.y; acc[0][2] += a0 * bv.z; acc[0][3] += a0 * bv.w;
            acc[1][0] += a1 * bv.x; acc[1][1] += a1 * bv.y; acc[1][2] += a1 * bv.z; acc[1][3] += a1 * bv.w;
            acc[2][0] += a2 * bv.x; acc[2][1] += a2 * bv.y; acc[2][2] += a2 * bv.z; acc[2][3] += a2 * bv.w;
            acc[3][0] += a3 * bv.x; acc[3][1] += a3 * bv.y; acc[3][2] += a3 * bv.z; acc[3][3] += a3 * bv.w;
        }
        __syncthreads();
    }
    float4 bias = *reinterpret_cast<const float4*>(&bh[n0 + tx * 4]);
#pragma unroll
    for (int i = 0; i < 4; i++) {
        int r = r0 + ty * 4 + i;
        int b = r >> 11;
        int t = r & (TT - 1);
        float4 o;
        o.x = acc[i][0] + bias.x;
        o.y = acc[i][1] + bias.y;
        o.z = acc[i][2] + bias.z;
        o.w = acc[i][3] + bias.w;
        *reinterpret_cast<float4*>(
            &out[((size_t)t * BB + b) * HH + n0 + tx * 4]) = o;
    }
}

// ---------------------------------------------------------------------------
// Kernel B: distributed scan, FENCE-FREE exchange.
// 256 WGs = 32 batches x 8 column slices, 1 WG/CU. Whh slice [512][64] in
// registers. Per step: slice matvec -> reduce -> tanh -> publish each h value
// as an 8B relaxed agent atomic {f32 val, u32 tag=t+1} -> each thread spins
// (relaxed 8B atomic load) on its one foreign slot -> refill LDS h.
// No release/acquire fences => no per-step L2 writeback/invalidate.
// Correctness: value+tag share one atomic word; the published value depends
// (true data dependence) on all prior-step reads, so it cannot become visible
// early. Double-buffered by t&1; tags are monotonic so a slot is only
// overwritten 2 steps later, after all its readers have advanced.
// Poison 0xAAAAAAAA never matches a wanted tag (1..2048) => no init needed.
// ---------------------------------------------------------------------------
__global__ __launch_bounds__(512) void scan_kernel(const float* __restrict__ Whh,
                                                   float* __restrict__ Y,
                                                   unsigned long long* __restrict__ ex) {
    __shared__ float h_lds[HH];
    __shared__ float part[NSL][SLW];
    const int tid = threadIdx.x;
    const int bid = blockIdx.x;
    const int s = bid >> 5;       // slice 0..7
    const int b = bid & 31;       // batch 0..31
    const int n0 = s * SLW;
    const int n  = tid & 63;
    const int kq = tid >> 6;      // 0..7
    const int k0 = kq * KPT;

    // one-time: Whh slice into registers, w[j] = Whh[k0+j][n0+n]
    float w[KPT];
#pragma unroll
    for (int j = 0; j < KPT; j++)
        w[j] = Whh[(size_t)(k0 + j) * HH + n0 + n];

    h_lds[tid] = 0.f;
    __syncthreads();

    // xw for t=0 (precomputed in place in Y)
    float xw_cur = 0.f;
    if (tid < SLW) xw_cur = Y[(size_t)b * HH + n0 + tid];

    // thread tid owns global column slot `tid` for the exchange-read phase;
    // own-slice slots (kq==s) are filled via LDS by the reducer instead.
    const bool foreign = (kq != s);

    for (int t = 0; t < TT; t++) {
        // slice matvec over h_{t-1} (LDS, uniform-address broadcast reads)
        float a0 = 0.f, a1 = 0.f, a2 = 0.f, a3 = 0.f;
#pragma unroll
        for (int j = 0; j < KPT; j += 4) {
            float4 h4 = *reinterpret_cast<const float4*>(&h_lds[k0 + j]);
            a0 += h4.x * w[j + 0];
            a1 += h4.y * w[j + 1];
            a2 += h4.z * w[j + 2];
            a3 += h4.w * w[j + 3];
        }
        part[kq][n] = (a0 + a1) + (a2 + a3);
        __syncthreads();

        if (tid < SLW) {
            float ssum = part[0][tid] + part[1][tid] + part[2][tid] + part[3][tid] +
                         part[4][tid] + part[5][tid] + part[6][tid] + part[7][tid] +
                         xw_cur;
            float hn = tanh_f(ssum);
            h_lds[n0 + tid] = hn;                                   // own slice
            Y[((size_t)t * BB + b) * HH + n0 + tid] = hn;           // output
            unsigned long long pk =
                ((unsigned long long)(unsigned)(t + 1) << 32) |
                (unsigned long long)__float_as_uint(hn);
            __hip_atomic_store(&ex[(((size_t)(t & 1) * BB + b) << 9) + n0 + tid],
                               pk, __ATOMIC_RELAXED, __HIP_MEMORY_SCOPE_AGENT);
        }

        if (t + 1 < TT) {
            // prefetch next xw while the exchange is in flight
            if (tid < SLW)
                xw_cur = Y[((size_t)(t + 1) * BB + b) * HH + n0 + tid];
            if (foreign) {
                unsigned long long* p =
                    &ex[(((size_t)(t & 1) * BB + b) << 9) + tid];
                const unsigned want = (unsigned)(t + 1);
                unsigned long long v;
                do {
                    v = __hip_atomic_load(p, __ATOMIC_RELAXED,
                                          __HIP_MEMORY_SCOPE_AGENT);
                } while ((unsigned)(v >> 32) != want);
                h_lds[tid] = __uint_as_float((unsigned)v);
            }
            __syncthreads();
        }
    }
}

// ---------------------------------------------------------------------------
// Kernel C: attention, one WG per batch.
//   scores[b,t] = tanh(Y[t,b,:] . v[b]),  v[b] = KW @ (QW^T Y[T-1,b])
// ---------------------------------------------------------------------------
__global__ __launch_bounds__(512) void attn_kernel(const float* __restrict__ QW,
                                                   const float* __restrict__ KW,
                                                   const float* __restrict__ Y,
                                                   float* __restrict__ c) {
    __shared__ float yl[HH];
    __shared__ float q0[DD];
    __shared__ float vv[HH];
    __shared__ float sc[TT];
    __shared__ float red[16];
    const int tid = threadIdx.x;
    const int b = blockIdx.x;
    const int w = tid >> 6;
    const int l = tid & 63;

    if (tid < HH) yl[tid] = Y[((size_t)(TT - 1) * BB + b) * HH + tid];
    __syncthreads();

    if (tid < DD) {
        float s = 0.f;
#pragma unroll 8
        for (int h = 0; h < HH; h++) s += yl[h] * QW[(size_t)h * DD + tid];
        q0[tid] = s;
    }
    __syncthreads();

    {
        float s = 0.f;
        const int nn = tid;
#pragma unroll 4
        for (int d = 0; d < DD; d += 4) {
            float4 kw = *reinterpret_cast<const float4*>(&KW[(size_t)nn * DD + d]);
            float4 q4 = *reinterpret_cast<const float4*>(&q0[d]);
            s += kw.x * q4.x + kw.y * q4.y + kw.z * q4.z + kw.w * q4.w;
        }
        vv[nn] = s;
    }
    __syncthreads();

    for (int i = 0; i < TT / 8; i++) {
        int t = i * 8 + w;
        const float* yr = &Y[((size_t)t * BB + b) * HH + l * 8];
        float4 y0 = *reinterpret_cast<const float4*>(yr);
        float4 y1 = *reinterpret_cast<const float4*>(yr + 4);
        float4 v0 = *reinterpret_cast<const float4*>(&vv[l * 8]);
        float4 v1 = *reinterpret_cast<const float4*>(&vv[l * 8 + 4]);
        float s = y0.x * v0.x + y0.y * v0.y + y0.z * v0.z + y0.w * v0.w +
                  y1.x * v1.x + y1.y * v1.y + y1.z * v1.z + y1.w * v1.w;
#pragma unroll
        for (int off = 32; off > 0; off >>= 1) s += __shfl_xor(s, off);
        if (l == 0) sc[t] = tanh_f(s);
    }
    __syncthreads();

    float m = -1e30f;
    for (int i = tid; i < TT; i += 512) m = fmaxf(m, sc[i]);
#pragma unroll
    for (int off = 32; off > 0; off >>= 1) m = fmaxf(m, __shfl_xor(m, off));
    if (l == 0) red[w] = m;
    __syncthreads();
    float gm = red[0];
#pragma unroll
    for (int i = 1; i < 8; i++) gm = fmaxf(gm, red[i]);

    float ls = 0.f;
    for (int i = tid; i < TT; i += 512) {
        float e = __expf(sc[i] - gm);
        sc[i] = e;
        ls += e;
    }
#pragma unroll
    for (int off = 32; off > 0; off >>= 1) ls += __shfl_xor(ls, off);
    __syncthreads();
    if (l == 0) red[8 + w] = ls;
    __syncthreads();
    float tot = 0.f;
#pragma unroll
    for (int i = 0; i < 8; i++) tot += red[8 + i];
    float inv = 1.f / tot;
    for (int i = tid; i < TT; i += 512) sc[i] *= inv;
    __syncthreads();

    {
        const int nn = tid;
        float acc = 0.f;
        for (int t = 0; t < TT; t += 4) {
            float4 a4 = *reinterpret_cast<const float4*>(&sc[t]);
            acc += a4.x * Y[((size_t)(t + 0) * BB + b) * HH + nn];
            acc += a4.y * Y[((size_t)(t + 1) * BB + b) * HH + nn];
            acc += a4.z * Y[((size_t)(t + 2) * BB + b) * HH + nn];
            acc += a4.w * Y[((size_t)(t + 3) * BB + b) * HH + nn];
        }
        c[(size_t)b * HH + nn] = acc;
    }
}

// ---------------------------------------------------------------------------
extern "C" void kernel_launch(void* const* d_in, const int* in_sizes, int n_in,
                              void* d_out, int out_size, void* d_ws, size_t ws_size,
                              hipStream_t stream) {
    const float* X   = (const float*)d_in[0];
    const float* Wxh = (const float*)d_in[1];
    const float* Whh = (const float*)d_in[2];
    const float* bh  = (const float*)d_in[3];
    const float* QW  = (const float*)d_in[4];
    const float* KW  = (const float*)d_in[5];
    float* out  = (float*)d_out;
    float* Ybuf = out;                              // [T][B][H]
    float* cbuf = out + (size_t)TT * BB * HH;       // [B][H]
    unsigned long long* ex = (unsigned long long*)d_ws;  // [2][BB][HH] 8B slots

    dim3 ga(BB * TT / 64, HH / 64);
    xw_gemm<<<ga, 256, 0, stream>>>(X, Wxh, bh, Ybuf);
    scan_kernel<<<BB * NSL, 512, 0, stream>>>(Whh, Ybuf, ex);
    attn_kernel<<<BB, 512, 0, stream>>>(QW, KW, Ybuf, cbuf);
}